// Round 25
// baseline (873.986 us; speedup 1.0000x reference)
//
#include <hip/hip_runtime.h>
#include <math.h>

#define HN   64
#define SNN  32
#define OSLN 32
#define LTN  63
#define KXN  144

#define OUT_HR 8257536
#define OUT_HC 8323072

// ws layout (floats)
#define WS_HROW 0              // [4][1024][64] = 262144
#define WS_HCOL 262144         // [4][1024][64] = 262144
#define WS_COS  524288         // [1024][32]
#define WS_SIN  557056
#define WS_FLG  589824         // 1024 flags x 32 uints, monotonic step counters

struct KParams {
  const float *x, *Wf, *Wq, *Bg, *Bq, *rcw, *rcb, *ccw, *ccb, *r_ow, *r_ob, *c_ow, *c_ob;
  float *ws;
  float *out;
};

__device__ __forceinline__ float bcast(float v, int k) {
  return __int_as_float(__builtin_amdgcn_readlane(__float_as_int(v), k));
}

// fast activations: v_exp_f32/v_rcp_f32 (measured R16: safe, absmax unchanged)
__device__ __forceinline__ float sigm_fast(float x) {
  return __builtin_amdgcn_rcpf(1.0f + __expf(-x));
}
__device__ __forceinline__ float tanh_fast(float x) {
  float a = fabsf(x);
  float e = __expf(-2.0f * a);
  float r = (1.0f - e) * __builtin_amdgcn_rcpf(1.0f + e);
  return copysignf(r, x);
}

// coherent (cache-bypassing, sc1) exchange: relaxed agent-scope atomics.
__device__ __forceinline__ float coh_load(const float* p) {
  return __uint_as_float(__hip_atomic_load((unsigned*)p, __ATOMIC_RELAXED, __HIP_MEMORY_SCOPE_AGENT));
}
__device__ __forceinline__ void coh_store(float* p, float v) {
  __hip_atomic_store((unsigned*)p, __float_as_uint(v), __ATOMIC_RELAXED, __HIP_MEMORY_SCOPE_AGENT);
}
__device__ __forceinline__ unsigned flag_load(const unsigned* p) {
  return __hip_atomic_load((unsigned*)p, __ATOMIC_RELAXED, __HIP_MEMORY_SCOPE_AGENT);
}
__device__ __forceinline__ void flag_store(unsigned* p, unsigned v) {
  __hip_atomic_store(p, v, __ATOMIC_RELAXED, __HIP_MEMORY_SCOPE_AGENT);
}
// flags[batch][side][group16], 32-uint (128B) padded
__device__ __forceinline__ unsigned* flg(float* ws, int b, int side, int grp) {
  return (unsigned*)(ws + WS_FLG) + ((((b << 1) | side) << 4) + grp) * 32;
}

__global__ void init_kernel(float* ws) {
  size_t i0 = (size_t)blockIdx.x * blockDim.x + threadIdx.x;
  size_t stride = (size_t)gridDim.x * blockDim.x;
  for (size_t i = i0; i < 524288; i += stride) ws[i] = 0.0f;          // 4-deep h buffers
  for (size_t i = i0; i < 32768; i += stride) {
    int ct = (int)(i >> 5);
    int f  = (int)(i & 31);
    float om = (6.2831853071795862f * (float)(f + 1)) * 0.03125f;
    float th = (float)ct * om;
    ws[WS_COS + i] = cosf(th);
    ws[WS_SIN + i] = sinf(th);
  }
  for (size_t i = i0; i < 32768; i += stride)
    ((unsigned*)(ws + WS_FLG))[i] = 0u;                               // flags
}

// 2-slot version of the hazard-batched readlane gate inner loop.
#define GATE_BATCH4(XC, W4, K0)                                          \
  {                                                                      \
    float t00 = bcast(XC[0], (K0)),     t01 = bcast(XC[1], (K0));        \
    float t10 = bcast(XC[0], (K0) + 1), t11 = bcast(XC[1], (K0) + 1);    \
    acc[0] = fmaf(W4.x, t00, acc[0]); acc[1] = fmaf(W4.x, t01, acc[1]);  \
    acc[0] = fmaf(W4.y, t10, acc[0]); acc[1] = fmaf(W4.y, t11, acc[1]);  \
    float u00 = bcast(XC[0], (K0) + 2), u01 = bcast(XC[1], (K0) + 2);    \
    float u10 = bcast(XC[0], (K0) + 3), u11 = bcast(XC[1], (K0) + 3);    \
    acc[0] = fmaf(W4.z, u00, acc[0]); acc[1] = fmaf(W4.z, u01, acc[1]);  \
    acc[0] = fmaf(W4.w, u10, acc[0]); acc[1] = fmaf(W4.w, u11, acc[1]);  \
  }

// 1024 blocks x 256 threads, 4 blocks/CU (4 waves/SIMD). R24 pairwise-flag
// structure with 2 chains/block: now that sync is local (max-of-2 producers),
// co-resident blocks stall independently and the extra TLP can hide sc1/flag
// latency (R9-R11's null TLP result was under the correlated batch barrier).
__global__ __launch_bounds__(256, 4) void fused_kernel(KParams p) {
  __shared__ float gl[2][224];    // gates: [0,64)=ug [64,128)=og [128,192)=ig [192,224)=freq
  __shared__ float hown[2][64];   // own-side h, persistent across steps
  __shared__ float cvec[2][64];   // row_c / col_c

  const int blk = blockIdx.x;
  const int b   = blk & 31;            // batch 0..31
  const int sub = blk >> 5;            // 0..31
  const bool isRow = (sub < 16);
  const int g   = sub & 15;            // chain group 0..15 (2 chains each)
  const int c0  = g << 1;              // first owned chain
  const int tid = threadIdx.x;
  const int lane = tid & 63;
  const int hh = tid >> 2, f0 = (tid & 3) << 3;   // state-phase mapping
  const int hp = tid & 63, mg = tid >> 6;         // out-phase mapping

  const int side  = isRow ? 0 : 1;
  unsigned* fOwn  = flg(p.ws, b, side, g);

  // ---- invariant setup ----
  const int j = (tid < 224) ? tid : 223;
  const float* Wrow; float bias;
  if (j < 192) {
    int jr = isRow ? ((j < 128) ? j : j + 128)
                   : ((j < 128) ? j + 128 : j + 192);
    Wrow = p.Wf + jr * KXN; bias = p.Bg[jr];
  } else {
    int jf = isRow ? (j - 192) : (j - 160);
    Wrow = p.Wq + jf * KXN; bias = p.Bq[jf];
  }
  float wfv[8];
  { const float* w = isRow ? p.rcw : p.ccw;
#pragma unroll
    for (int fi = 0; fi < 8; ++fi) wfv[fi] = w[f0 + fi]; }
  const float cbv = isRow ? p.rcb[0] : p.ccb[0];
  const float ob  = (isRow ? p.r_ob : p.c_ob)[hp];
  const float* OW = (isRow ? p.r_ow : p.c_ow) + hp * HN;

  // persistent oscillator state (slot i, freq f0+fi)
  float rr[2][8], ri[2][8];
#pragma unroll
  for (int i = 0; i < 2; ++i)
#pragma unroll
    for (int fi = 0; fi < 8; ++fi) { rr[i][fi] = 0.1f; ri[i][fi] = 0.1f; }

  // own h starts at zero
  if (tid < 128) hown[tid >> 6][tid & 63] = 0.0f;
  __syncthreads();

  for (int t = 0; t < LTN; ++t) {
    // ---- SYNC-IN: wait for the <=2 cross-side producer groups of step t-1 ----
    if (t > 0) {
      if (tid == 0) {
        int a = isRow ? ((c0 - t) & 31) : ((c0 + t) & 31);   // first cross chain
        unsigned* f1 = flg(p.ws, b, 1 - side, a >> 1);
        unsigned* f2 = flg(p.ws, b, 1 - side, ((a + 1) & 31) >> 1);
        const unsigned need = (unsigned)t;
        int guard = 0;
        while ((flag_load(f1) < need || flag_load(f2) < need) && ++guard < 4000000)
          __builtin_amdgcn_s_sleep(1);
      }
      __syncthreads();
    }

    int r8[2], cc8[2];
#pragma unroll
    for (int i = 0; i < 2; ++i) {
      int ch = c0 + i;
      r8[i]  = isRow ? ch : ((ch + t) & 31);
      cc8[i] = isRow ? ((ch - t) & 31) : ch;
    }
    const float* hrowR = p.ws + WS_HROW + (size_t)(t & 3) * 65536;
    float*       hrowW = p.ws + WS_HROW + (size_t)((t + 1) & 3) * 65536;
    const float* hcolR = p.ws + WS_HCOL + (size_t)(t & 3) * 65536;
    float*       hcolW = p.ws + WS_HCOL + (size_t)((t + 1) & 3) * 65536;

    // ---- phase A: xcat load (own h from LDS, cross h via sc1) + gate GEMM ----
    float xc0[2], xc1[2], xc2[2];
#pragma unroll
    for (int i = 0; i < 2; ++i) {
      int r = r8[i], cc = cc8[i];
      int cdx = t - r;
      bool av = (cdx >= 0) && (cdx < OSLN);
      if (isRow) {
        xc0[i] = hown[i][lane];                                    // own (block-local)
        xc1[i] = coh_load(&hcolR[(((cc << 5) | b) << 6) + lane]);  // cross
      } else {
        xc1[i] = hown[i][lane];                                    // own (block-local)
        xc0[i] = coh_load(&hrowR[(((r << 5) | b) << 6) + lane]);   // cross
      }
      xc2[i] = (av && lane < 16) ? p.x[(size_t)((((b << 5) | r) << 5) | cdx) * 16 + lane] : 0.0f;
    }
    float acc[2] = {0.f, 0.f};
    for (int kb = 0; kb < 64; kb += 4) {
      float4 w4 = *(const float4*)(Wrow + kb);
      GATE_BATCH4(xc0, w4, kb);
    }
    for (int kb = 64; kb < 128; kb += 4) {
      float4 w4 = *(const float4*)(Wrow + kb);
      GATE_BATCH4(xc1, w4, kb - 64);
    }
#pragma unroll
    for (int kb = 128; kb < 144; kb += 4) {
      float4 w4 = *(const float4*)(Wrow + kb);
      GATE_BATCH4(xc2, w4, kb - 128);
    }
    if (tid < 224) {
      const bool isT = (tid >= 128 && tid < 192);
#pragma unroll
      for (int i = 0; i < 2; ++i) {
        float bm = (t < SNN && r8[i] <= t) ? 1.0f : 0.0f;
        float v = fmaf(bm, bias, acc[i]);
        gl[i][tid] = isT ? tanh_fast(v) : sigm_fast(v);
      }
    }
    __syncthreads();

    // ---- phase B: register-state update + cvec ----
#pragma unroll
    for (int i = 0; i < 2; ++i) {
      int cc = cc8[i];
      int tcd = t - cc;
      int ctI = (tcd >= 0 && tcd < OSLN) ? ((cc << 5) + tcd) : 0;
      const float* cp = p.ws + WS_COS + (ctI << 5) + f0;
      const float* sp = p.ws + WS_SIN + (ctI << 5) + f0;
      float csv[8], snv[8];
      *(float4*)(csv)     = *(const float4*)(cp);
      *(float4*)(csv + 4) = *(const float4*)(cp + 4);
      *(float4*)(snv)     = *(const float4*)(sp);
      *(float4*)(snv + 4) = *(const float4*)(sp + 4);
      float ug = gl[i][hh];
      float og = gl[i][64 + hh];
      float ig = gl[i][128 + hh];
      float amp = og * ig;
      float fr[8];
      *(float4*)(fr)     = *(const float4*)(&gl[i][192 + f0]);
      *(float4*)(fr + 4) = *(const float4*)(&gl[i][192 + f0 + 4]);
      float sq = 0.0f;
#pragma unroll
      for (int fi = 0; fi < 8; ++fi) {
        float ft = ug * fr[fi];
        rr[i][fi] = fmaf(ft, rr[i][fi], amp * csv[fi]);
        ri[i][fi] = fmaf(ft, ri[i][fi], amp * snv[fi]);
        sq = fmaf(fmaf(ri[i][fi], ri[i][fi], rr[i][fi] * rr[i][fi]), wfv[fi], sq);
      }
      sq += __shfl_xor(sq, 1);
      sq += __shfl_xor(sq, 2);
      if ((tid & 3) == 0) cvec[i][hh] = tanh_fast(sq + cbv);
    }
    __syncthreads();

    // ---- phase C: output matmul + h update + stores (waves 0,1 -> slots 0,1) ----
    if (mg < 2) {
      const int i = mg;
      float u0 = 0.0f;
      for (int k = 0; k < 64; k += 4) {
        float4 w4 = *(const float4*)(OW + k);
        u0 = fmaf(w4.x, cvec[i][k],     u0);
        u0 = fmaf(w4.y, cvec[i][k + 1], u0);
        u0 = fmaf(w4.z, cvec[i][k + 2], u0);
        u0 = fmaf(w4.w, cvec[i][k + 3], u0);
      }
      float ug = gl[i][hp];
      float ig = gl[i][128 + hp];
      float hOld = hown[i][hp];          // own previous h (one-to-one read/write)
      float cval = cvec[i][hp];
      float pre = (1.0f - ug) * hOld + ug * ig + u0 + ob;
      float hn = sigm_fast(pre) * cval;
      hown[i][hp] = hn;                  // persist own h locally for step t+1
      int r = r8[i], cc = cc8[i];
      int n = (r << 5) | b;
      if (isRow) {
        coh_store(&hrowW[(n << 6) + hp], hn);                 // for col-side readers
        p.out[(((size_t)n * LTN) + t) * 128 + hp] = hn;
        if (t >= 31 && r == t - 31)
          p.out[OUT_HR + (((b << 5) | r) << 6) + hp] = hn;
      } else {
        coh_store(&hcolW[(((cc << 5) | b) << 6) + hp], hn);   // for row-side readers
        p.out[(((size_t)n * LTN) + t) * 128 + 64 + hp] = hn;
        if (t >= 31 && r == 31)
          p.out[OUT_HC + (((b << 5) | (t - 31)) << 6) + hp] = hn;
      }
    }

    // ---- SYNC-OUT: drain stores (syncthreads emits vmcnt(0)), publish flag ----
    if (t < LTN - 1) {
      __syncthreads();
      if (tid == 0) flag_store(fOwn, (unsigned)(t + 1));
    }
  }
}

extern "C" void kernel_launch(void* const* d_in, const int* in_sizes, int n_in,
                              void* d_out, int out_size, void* d_ws, size_t ws_size,
                              hipStream_t stream) {
  KParams p;
  p.x    = (const float*)d_in[0];
  p.Wf   = (const float*)d_in[1];
  p.Wq   = (const float*)d_in[2];
  p.Bg   = (const float*)d_in[3];
  p.Bq   = (const float*)d_in[4];
  p.rcw  = (const float*)d_in[5];
  p.rcb  = (const float*)d_in[6];
  p.ccw  = (const float*)d_in[7];
  p.ccb  = (const float*)d_in[8];
  p.r_ow = (const float*)d_in[9];
  p.r_ob = (const float*)d_in[10];
  p.c_ow = (const float*)d_in[11];
  p.c_ob = (const float*)d_in[12];
  p.ws   = (float*)d_ws;
  p.out  = (float*)d_out;

  hipLaunchKernelGGL(init_kernel, dim3(256), dim3(256), 0, stream, p.ws);
  hipLaunchKernelGGL(fused_kernel, dim3(1024), dim3(256), 0, stream, p);
}

// Round 26
// 741.450 us; speedup vs baseline: 1.1788x; 1.1788x over previous
//
#include <hip/hip_runtime.h>
#include <math.h>

#define HN   64
#define SNN  32
#define OSLN 32
#define LTN  63
#define KXN  144

#define OUT_HR 8257536
#define OUT_HC 8323072

// ws layout (floats)
#define WS_HROW 0              // [4][1024][64] = 262144
#define WS_HCOL 262144         // [4][1024][64] = 262144
#define WS_COS  524288         // [1024][32]
#define WS_SIN  557056
#define WS_FLG  589824         // 512 flags x 32 uints (128B-padded), monotonic step counters

struct KParams {
  const float *x, *Wf, *Wq, *Bg, *Bq, *rcw, *rcb, *ccw, *ccb, *r_ow, *r_ob, *c_ow, *c_ob;
  float *ws;
  float *out;
};

__device__ __forceinline__ float bcast(float v, int k) {
  return __int_as_float(__builtin_amdgcn_readlane(__float_as_int(v), k));
}

// fast activations: v_exp_f32/v_rcp_f32 (measured R16: safe, absmax unchanged)
__device__ __forceinline__ float sigm_fast(float x) {
  return __builtin_amdgcn_rcpf(1.0f + __expf(-x));
}
__device__ __forceinline__ float tanh_fast(float x) {
  float a = fabsf(x);
  float e = __expf(-2.0f * a);
  float r = (1.0f - e) * __builtin_amdgcn_rcpf(1.0f + e);
  return copysignf(r, x);
}

// coherent (cache-bypassing, sc1) exchange: relaxed agent-scope atomics.
__device__ __forceinline__ float coh_load(const float* p) {
  return __uint_as_float(__hip_atomic_load((unsigned*)p, __ATOMIC_RELAXED, __HIP_MEMORY_SCOPE_AGENT));
}
__device__ __forceinline__ void coh_store(float* p, float v) {
  __hip_atomic_store((unsigned*)p, __float_as_uint(v), __ATOMIC_RELAXED, __HIP_MEMORY_SCOPE_AGENT);
}
__device__ __forceinline__ unsigned flag_load(const unsigned* p) {
  return __hip_atomic_load((unsigned*)p, __ATOMIC_RELAXED, __HIP_MEMORY_SCOPE_AGENT);
}
__device__ __forceinline__ void flag_store(unsigned* p, unsigned v) {
  __hip_atomic_store(p, v, __ATOMIC_RELAXED, __HIP_MEMORY_SCOPE_AGENT);
}
// flags[batch][side][group], 32-uint (128B) padded
__device__ __forceinline__ unsigned* flg(float* ws, int b, int side, int grp) {
  return (unsigned*)(ws + WS_FLG) + ((((b << 1) | side) << 3) + grp) * 32;
}

__global__ void init_kernel(float* ws) {
  size_t i0 = (size_t)blockIdx.x * blockDim.x + threadIdx.x;
  size_t stride = (size_t)gridDim.x * blockDim.x;
  for (size_t i = i0; i < 524288; i += stride) ws[i] = 0.0f;          // 4-deep h buffers
  for (size_t i = i0; i < 32768; i += stride) {
    int ct = (int)(i >> 5);
    int f  = (int)(i & 31);
    float om = (6.2831853071795862f * (float)(f + 1)) * 0.03125f;
    float th = (float)ct * om;
    ws[WS_COS + i] = cosf(th);
    ws[WS_SIN + i] = sinf(th);
  }
  for (size_t i = i0; i < 16384; i += stride)
    ((unsigned*)(ws + WS_FLG))[i] = 0u;                               // flags
}

// 8 independent readlanes batched before their 8 consuming FMAs (R18, kept).
#define GATE_BATCH8(XC, W4, K0)                                          \
  {                                                                      \
    float t00 = bcast(XC[0], (K0)),     t01 = bcast(XC[1], (K0));        \
    float t02 = bcast(XC[2], (K0)),     t03 = bcast(XC[3], (K0));        \
    float t10 = bcast(XC[0], (K0) + 1), t11 = bcast(XC[1], (K0) + 1);    \
    float t12 = bcast(XC[2], (K0) + 1), t13 = bcast(XC[3], (K0) + 1);    \
    acc[0] = fmaf(W4.x, t00, acc[0]); acc[1] = fmaf(W4.x, t01, acc[1]);  \
    acc[2] = fmaf(W4.x, t02, acc[2]); acc[3] = fmaf(W4.x, t03, acc[3]);  \
    acc[0] = fmaf(W4.y, t10, acc[0]); acc[1] = fmaf(W4.y, t11, acc[1]);  \
    acc[2] = fmaf(W4.y, t12, acc[2]); acc[3] = fmaf(W4.y, t13, acc[3]);  \
    float u00 = bcast(XC[0], (K0) + 2), u01 = bcast(XC[1], (K0) + 2);    \
    float u02 = bcast(XC[2], (K0) + 2), u03 = bcast(XC[3], (K0) + 2);    \
    float u10 = bcast(XC[0], (K0) + 3), u11 = bcast(XC[1], (K0) + 3);    \
    float u12 = bcast(XC[2], (K0) + 3), u13 = bcast(XC[3], (K0) + 3);    \
    acc[0] = fmaf(W4.z, u00, acc[0]); acc[1] = fmaf(W4.z, u01, acc[1]);  \
    acc[2] = fmaf(W4.z, u02, acc[2]); acc[3] = fmaf(W4.z, u03, acc[3]);  \
    acc[0] = fmaf(W4.w, u10, acc[0]); acc[1] = fmaf(W4.w, u11, acc[1]);  \
    acc[2] = fmaf(W4.w, u12, acc[2]); acc[3] = fmaf(W4.w, u13, acc[3]);  \
  }

// 512 blocks x 256 threads, 2 blocks/CU (R24 measured-best shape).
// R24 pairwise-flag structure + FLAG-WAIT HIDDEN UNDER OWN-GEMM: the own-side
// 64-k GEMM (block-local LDS h) and the x-part have no dependency on the
// cross-side producers, so they run BEFORE the flag wait; the wait (producer
// skew, ~1-2us) is absorbed under ~1us of own-GEMM issue instead of
// serializing at step start. Cross loads + cross GEMM follow the wait.
__global__ __launch_bounds__(256, 2) void fused_kernel(KParams p) {
  __shared__ float gl[4][224];    // gates: [0,64)=ug [64,128)=og [128,192)=ig [192,224)=freq
  __shared__ float hown[4][64];   // own-side h, persistent across steps
  __shared__ float cvec[4][64];   // row_c / col_c

  const int blk = blockIdx.x;
  const int b   = blk & 31;            // batch 0..31
  const int sub = blk >> 5;            // 0..15
  const bool isRow = (sub < 8);
  const int g   = sub & 7;             // chain group 0..7
  const int c0  = g << 2;              // first owned chain
  const int tid = threadIdx.x;
  const int lane = tid & 63;
  const int hh = tid >> 2, f0 = (tid & 3) << 3;   // state-phase mapping
  const int hp = tid & 63, mg = tid >> 6;         // out-phase mapping (slot = mg)

  const int side  = isRow ? 0 : 1;
  unsigned* fOwn  = flg(p.ws, b, side, g);

  // ---- invariant setup ----
  const int j = (tid < 224) ? tid : 223;
  const float* Wrow; float bias;
  if (j < 192) {
    int jr = isRow ? ((j < 128) ? j : j + 128)
                   : ((j < 128) ? j + 128 : j + 192);
    Wrow = p.Wf + jr * KXN; bias = p.Bg[jr];
  } else {
    int jf = isRow ? (j - 192) : (j - 160);
    Wrow = p.Wq + jf * KXN; bias = p.Bq[jf];
  }
  float wfv[8];
  { const float* w = isRow ? p.rcw : p.ccw;
#pragma unroll
    for (int fi = 0; fi < 8; ++fi) wfv[fi] = w[f0 + fi]; }
  const float cbv = isRow ? p.rcb[0] : p.ccb[0];
  const float ob  = (isRow ? p.r_ob : p.c_ob)[hp];
  const float* OW = (isRow ? p.r_ow : p.c_ow) + hp * HN;

  // persistent oscillator state (slot i, freq f0+fi)
  float rr[4][8], ri[4][8];
#pragma unroll
  for (int i = 0; i < 4; ++i)
#pragma unroll
    for (int fi = 0; fi < 8; ++fi) { rr[i][fi] = 0.1f; ri[i][fi] = 0.1f; }

  // own h starts at zero
  hown[mg][hp] = 0.0f;
  __syncthreads();

  for (int t = 0; t < LTN; ++t) {
    int r8[4], cc8[4];
#pragma unroll
    for (int i = 0; i < 4; ++i) {
      int ch = c0 + i;
      r8[i]  = isRow ? ch : ((ch + t) & 31);
      cc8[i] = isRow ? ((ch - t) & 31) : ch;
    }
    const float* hrowR = p.ws + WS_HROW + (size_t)(t & 3) * 65536;
    float*       hrowW = p.ws + WS_HROW + (size_t)((t + 1) & 3) * 65536;
    const float* hcolR = p.ws + WS_HCOL + (size_t)(t & 3) * 65536;
    float*       hcolW = p.ws + WS_HCOL + (size_t)((t + 1) & 3) * 65536;

    // ---- phase A1: own xcat (LDS) + x; own GEMM + x GEMM (no cross dependency) ----
    float xcO[4], xcC[4], xc2[4];
#pragma unroll
    for (int i = 0; i < 4; ++i) {
      int r = r8[i];
      int cdx = t - r;
      bool av = (cdx >= 0) && (cdx < OSLN);
      xcO[i] = hown[i][lane];
      xc2[i] = (av && lane < 16) ? p.x[(size_t)((((b << 5) | r) << 5) | cdx) * 16 + lane] : 0.0f;
    }
    float acc[4] = {0.f,0.f,0.f,0.f};
    {
      const int ownBase = isRow ? 0 : 64;     // own part of W row
      for (int kb = 0; kb < 64; kb += 4) {
        float4 w4 = *(const float4*)(Wrow + ownBase + kb);
        GATE_BATCH8(xcO, w4, kb);
      }
#pragma unroll
      for (int kb = 128; kb < 144; kb += 4) {
        float4 w4 = *(const float4*)(Wrow + kb);
        GATE_BATCH8(xc2, w4, kb - 128);
      }
    }

    // ---- SYNC-IN (hidden under own GEMM): wait <=2 cross producer groups ----
    if (t > 0) {
      if (tid == 0) {
        int a = isRow ? ((c0 - t) & 31) : ((c0 + t) & 31);   // first cross chain
        unsigned* f1 = flg(p.ws, b, 1 - side, a >> 2);
        unsigned* f2 = flg(p.ws, b, 1 - side, ((a + 3) & 31) >> 2);
        const unsigned need = (unsigned)t;
        int guard = 0;
        while ((flag_load(f1) < need || flag_load(f2) < need) && ++guard < 4000000)
          __builtin_amdgcn_s_sleep(1);
      }
      __syncthreads();
    }

    // ---- phase A2: cross loads (sc1) + cross GEMM ----
#pragma unroll
    for (int i = 0; i < 4; ++i) {
      int r = r8[i], cc = cc8[i];
      xcC[i] = isRow ? coh_load(&hcolR[(((cc << 5) | b) << 6) + lane])
                     : coh_load(&hrowR[(((r << 5) | b) << 6) + lane]);
    }
    {
      const int crossBase = isRow ? 64 : 0;   // cross part of W row
      for (int kb = 0; kb < 64; kb += 4) {
        float4 w4 = *(const float4*)(Wrow + crossBase + kb);
        GATE_BATCH8(xcC, w4, kb);
      }
    }
    if (tid < 224) {
      const bool isT = (tid >= 128 && tid < 192);
#pragma unroll
      for (int i = 0; i < 4; ++i) {
        float bm = (t < SNN && r8[i] <= t) ? 1.0f : 0.0f;
        float v = fmaf(bm, bias, acc[i]);
        gl[i][tid] = isT ? tanh_fast(v) : sigm_fast(v);
      }
    }
    __syncthreads();

    // ---- phase B: register-state update + cvec ----
#pragma unroll
    for (int i = 0; i < 4; ++i) {
      int cc = cc8[i];
      int tcd = t - cc;
      int ctI = (tcd >= 0 && tcd < OSLN) ? ((cc << 5) + tcd) : 0;
      const float* cp = p.ws + WS_COS + (ctI << 5) + f0;
      const float* sp = p.ws + WS_SIN + (ctI << 5) + f0;
      float csv[8], snv[8];
      *(float4*)(csv)     = *(const float4*)(cp);
      *(float4*)(csv + 4) = *(const float4*)(cp + 4);
      *(float4*)(snv)     = *(const float4*)(sp);
      *(float4*)(snv + 4) = *(const float4*)(sp + 4);
      float ug = gl[i][hh];
      float og = gl[i][64 + hh];
      float ig = gl[i][128 + hh];
      float amp = og * ig;
      float fr[8];
      *(float4*)(fr)     = *(const float4*)(&gl[i][192 + f0]);
      *(float4*)(fr + 4) = *(const float4*)(&gl[i][192 + f0 + 4]);
      float sq = 0.0f;
#pragma unroll
      for (int fi = 0; fi < 8; ++fi) {
        float ft = ug * fr[fi];
        rr[i][fi] = fmaf(ft, rr[i][fi], amp * csv[fi]);
        ri[i][fi] = fmaf(ft, ri[i][fi], amp * snv[fi]);
        sq = fmaf(fmaf(ri[i][fi], ri[i][fi], rr[i][fi] * rr[i][fi]), wfv[fi], sq);
      }
      sq += __shfl_xor(sq, 1);
      sq += __shfl_xor(sq, 2);
      if ((tid & 3) == 0) cvec[i][hh] = tanh_fast(sq + cbv);
    }
    __syncthreads();

    // ---- phase C: output matmul + h update + stores (slot = mg) ----
    float u0 = 0.0f;
    for (int k = 0; k < 64; k += 4) {
      float4 w4 = *(const float4*)(OW + k);
      u0 = fmaf(w4.x, cvec[mg][k],     u0);
      u0 = fmaf(w4.y, cvec[mg][k + 1], u0);
      u0 = fmaf(w4.z, cvec[mg][k + 2], u0);
      u0 = fmaf(w4.w, cvec[mg][k + 3], u0);
    }
    {
      const int i = mg;
      float ug = gl[i][hp];
      float ig = gl[i][128 + hp];
      float hOld = hown[i][hp];          // own previous h (one-to-one read/write)
      float cval = cvec[i][hp];
      float pre = (1.0f - ug) * hOld + ug * ig + u0 + ob;
      float hn = sigm_fast(pre) * cval;
      hown[i][hp] = hn;                  // persist own h locally for step t+1
      int r = r8[i], cc = cc8[i];
      int n = (r << 5) | b;
      if (isRow) {
        coh_store(&hrowW[(n << 6) + hp], hn);                 // for col-side readers
        p.out[(((size_t)n * LTN) + t) * 128 + hp] = hn;
        if (t >= 31 && r == t - 31)
          p.out[OUT_HR + (((b << 5) | r) << 6) + hp] = hn;
      } else {
        coh_store(&hcolW[(((cc << 5) | b) << 6) + hp], hn);   // for row-side readers
        p.out[(((size_t)n * LTN) + t) * 128 + 64 + hp] = hn;
        if (t >= 31 && r == 31)
          p.out[OUT_HC + (((b << 5) | (t - 31)) << 6) + hp] = hn;
      }
    }

    // ---- SYNC-OUT: drain stores (syncthreads emits vmcnt(0)), publish flag ----
    if (t < LTN - 1) {
      __syncthreads();
      if (tid == 0) flag_store(fOwn, (unsigned)(t + 1));
    }
  }
}

extern "C" void kernel_launch(void* const* d_in, const int* in_sizes, int n_in,
                              void* d_out, int out_size, void* d_ws, size_t ws_size,
                              hipStream_t stream) {
  KParams p;
  p.x    = (const float*)d_in[0];
  p.Wf   = (const float*)d_in[1];
  p.Wq   = (const float*)d_in[2];
  p.Bg   = (const float*)d_in[3];
  p.Bq   = (const float*)d_in[4];
  p.rcw  = (const float*)d_in[5];
  p.rcb  = (const float*)d_in[6];
  p.ccw  = (const float*)d_in[7];
  p.ccb  = (const float*)d_in[8];
  p.r_ow = (const float*)d_in[9];
  p.r_ob = (const float*)d_in[10];
  p.c_ow = (const float*)d_in[11];
  p.c_ob = (const float*)d_in[12];
  p.ws   = (float*)d_ws;
  p.out  = (float*)d_out;

  hipLaunchKernelGGL(init_kernel, dim3(256), dim3(256), 0, stream, p.ws);
  hipLaunchKernelGGL(fused_kernel, dim3(512), dim3(256), 0, stream, p);
}

// Round 27
// 738.158 us; speedup vs baseline: 1.1840x; 1.0045x over previous
//
#include <hip/hip_runtime.h>
#include <math.h>

#define HN   64
#define SNN  32
#define OSLN 32
#define LTN  63
#define KXN  144

#define OUT_HR 8257536
#define OUT_HC 8323072

// ws layout (floats)
#define WS_HROW 0              // [4][1024][64] = 262144
#define WS_HCOL 262144         // [4][1024][64] = 262144
#define WS_COS  524288         // [1024][32]
#define WS_SIN  557056
#define WS_FLG  589824         // 512 flags x 32 uints (128B-padded), monotonic step counters

struct KParams {
  const float *x, *Wf, *Wq, *Bg, *Bq, *rcw, *rcb, *ccw, *ccb, *r_ow, *r_ob, *c_ow, *c_ob;
  float *ws;
  float *out;
};

__device__ __forceinline__ float bcast(float v, int k) {
  return __int_as_float(__builtin_amdgcn_readlane(__float_as_int(v), k));
}

// fast activations: v_exp_f32/v_rcp_f32 (measured R16: safe, absmax unchanged)
__device__ __forceinline__ float sigm_fast(float x) {
  return __builtin_amdgcn_rcpf(1.0f + __expf(-x));
}
__device__ __forceinline__ float tanh_fast(float x) {
  float a = fabsf(x);
  float e = __expf(-2.0f * a);
  float r = (1.0f - e) * __builtin_amdgcn_rcpf(1.0f + e);
  return copysignf(r, x);
}

// coherent (cache-bypassing, sc1) exchange: relaxed agent-scope atomics.
__device__ __forceinline__ float coh_load(const float* p) {
  return __uint_as_float(__hip_atomic_load((unsigned*)p, __ATOMIC_RELAXED, __HIP_MEMORY_SCOPE_AGENT));
}
__device__ __forceinline__ void coh_store(float* p, float v) {
  __hip_atomic_store((unsigned*)p, __float_as_uint(v), __ATOMIC_RELAXED, __HIP_MEMORY_SCOPE_AGENT);
}
__device__ __forceinline__ unsigned flag_load(const unsigned* p) {
  return __hip_atomic_load((unsigned*)p, __ATOMIC_RELAXED, __HIP_MEMORY_SCOPE_AGENT);
}
__device__ __forceinline__ void flag_store(unsigned* p, unsigned v) {
  __hip_atomic_store(p, v, __ATOMIC_RELAXED, __HIP_MEMORY_SCOPE_AGENT);
}
// flags[batch][side][group], 32-uint (128B) padded
__device__ __forceinline__ unsigned* flg(float* ws, int b, int side, int grp) {
  return (unsigned*)(ws + WS_FLG) + ((((b << 1) | side) << 3) + grp) * 32;
}

__global__ void init_kernel(float* ws) {
  size_t i0 = (size_t)blockIdx.x * blockDim.x + threadIdx.x;
  size_t stride = (size_t)gridDim.x * blockDim.x;
  for (size_t i = i0; i < 524288; i += stride) ws[i] = 0.0f;          // 4-deep h buffers
  for (size_t i = i0; i < 32768; i += stride) {
    int ct = (int)(i >> 5);
    int f  = (int)(i & 31);
    float om = (6.2831853071795862f * (float)(f + 1)) * 0.03125f;
    float th = (float)ct * om;
    ws[WS_COS + i] = cosf(th);
    ws[WS_SIN + i] = sinf(th);
  }
  for (size_t i = i0; i < 16384; i += stride)
    ((unsigned*)(ws + WS_FLG))[i] = 0u;                               // flags
}

// 8 independent readlanes batched before their 8 consuming FMAs (R18, kept).
#define GATE_BATCH8(XC, W4, K0)                                          \
  {                                                                      \
    float t00 = bcast(XC[0], (K0)),     t01 = bcast(XC[1], (K0));        \
    float t02 = bcast(XC[2], (K0)),     t03 = bcast(XC[3], (K0));        \
    float t10 = bcast(XC[0], (K0) + 1), t11 = bcast(XC[1], (K0) + 1);    \
    float t12 = bcast(XC[2], (K0) + 1), t13 = bcast(XC[3], (K0) + 1);    \
    acc[0] = fmaf(W4.x, t00, acc[0]); acc[1] = fmaf(W4.x, t01, acc[1]);  \
    acc[2] = fmaf(W4.x, t02, acc[2]); acc[3] = fmaf(W4.x, t03, acc[3]);  \
    acc[0] = fmaf(W4.y, t10, acc[0]); acc[1] = fmaf(W4.y, t11, acc[1]);  \
    acc[2] = fmaf(W4.y, t12, acc[2]); acc[3] = fmaf(W4.y, t13, acc[3]);  \
    float u00 = bcast(XC[0], (K0) + 2), u01 = bcast(XC[1], (K0) + 2);    \
    float u02 = bcast(XC[2], (K0) + 2), u03 = bcast(XC[3], (K0) + 2);    \
    float u10 = bcast(XC[0], (K0) + 3), u11 = bcast(XC[1], (K0) + 3);    \
    float u12 = bcast(XC[2], (K0) + 3), u13 = bcast(XC[3], (K0) + 3);    \
    acc[0] = fmaf(W4.z, u00, acc[0]); acc[1] = fmaf(W4.z, u01, acc[1]);  \
    acc[2] = fmaf(W4.z, u02, acc[2]); acc[3] = fmaf(W4.z, u03, acc[3]);  \
    acc[0] = fmaf(W4.w, u10, acc[0]); acc[1] = fmaf(W4.w, u11, acc[1]);  \
    acc[2] = fmaf(W4.w, u12, acc[2]); acc[3] = fmaf(W4.w, u13, acc[3]);  \
  }

// 512 blocks x 256 threads, 2 blocks/CU (R24/R26 measured-best shape).
// R26 structure + CROSS-LOAD RTT HIDDEN UNDER x-GEMM: order is now
//   own GEMM -> flag wait -> ISSUE cross sc1 loads -> x GEMM (covers RTT)
//   -> cross GEMM.
// The x-part depends only on p.x (no producer dependency) so it is legal
// to move it behind the wait; per-acc accumulation sequence (own, x, cross)
// is unchanged from R26 -> bit-identical numerics.
__global__ __launch_bounds__(256, 2) void fused_kernel(KParams p) {
  __shared__ float gl[4][224];    // gates: [0,64)=ug [64,128)=og [128,192)=ig [192,224)=freq
  __shared__ float hown[4][64];   // own-side h, persistent across steps
  __shared__ float cvec[4][64];   // row_c / col_c

  const int blk = blockIdx.x;
  const int b   = blk & 31;            // batch 0..31
  const int sub = blk >> 5;            // 0..15
  const bool isRow = (sub < 8);
  const int g   = sub & 7;             // chain group 0..7
  const int c0  = g << 2;              // first owned chain
  const int tid = threadIdx.x;
  const int lane = tid & 63;
  const int hh = tid >> 2, f0 = (tid & 3) << 3;   // state-phase mapping
  const int hp = tid & 63, mg = tid >> 6;         // out-phase mapping (slot = mg)

  const int side  = isRow ? 0 : 1;
  unsigned* fOwn  = flg(p.ws, b, side, g);

  // ---- invariant setup ----
  const int j = (tid < 224) ? tid : 223;
  const float* Wrow; float bias;
  if (j < 192) {
    int jr = isRow ? ((j < 128) ? j : j + 128)
                   : ((j < 128) ? j + 128 : j + 192);
    Wrow = p.Wf + jr * KXN; bias = p.Bg[jr];
  } else {
    int jf = isRow ? (j - 192) : (j - 160);
    Wrow = p.Wq + jf * KXN; bias = p.Bq[jf];
  }
  float wfv[8];
  { const float* w = isRow ? p.rcw : p.ccw;
#pragma unroll
    for (int fi = 0; fi < 8; ++fi) wfv[fi] = w[f0 + fi]; }
  const float cbv = isRow ? p.rcb[0] : p.ccb[0];
  const float ob  = (isRow ? p.r_ob : p.c_ob)[hp];
  const float* OW = (isRow ? p.r_ow : p.c_ow) + hp * HN;

  // persistent oscillator state (slot i, freq f0+fi)
  float rr[4][8], ri[4][8];
#pragma unroll
  for (int i = 0; i < 4; ++i)
#pragma unroll
    for (int fi = 0; fi < 8; ++fi) { rr[i][fi] = 0.1f; ri[i][fi] = 0.1f; }

  // own h starts at zero
  hown[mg][hp] = 0.0f;
  __syncthreads();

  for (int t = 0; t < LTN; ++t) {
    int r8[4], cc8[4];
#pragma unroll
    for (int i = 0; i < 4; ++i) {
      int ch = c0 + i;
      r8[i]  = isRow ? ch : ((ch + t) & 31);
      cc8[i] = isRow ? ((ch - t) & 31) : ch;
    }
    const float* hrowR = p.ws + WS_HROW + (size_t)(t & 3) * 65536;
    float*       hrowW = p.ws + WS_HROW + (size_t)((t + 1) & 3) * 65536;
    const float* hcolR = p.ws + WS_HCOL + (size_t)(t & 3) * 65536;
    float*       hcolW = p.ws + WS_HCOL + (size_t)((t + 1) & 3) * 65536;

    // ---- phase A1: own xcat (LDS) + x loads; own GEMM (no cross dependency) ----
    float xcO[4], xcC[4], xc2[4];
#pragma unroll
    for (int i = 0; i < 4; ++i) {
      int r = r8[i];
      int cdx = t - r;
      bool av = (cdx >= 0) && (cdx < OSLN);
      xcO[i] = hown[i][lane];
      xc2[i] = (av && lane < 16) ? p.x[(size_t)((((b << 5) | r) << 5) | cdx) * 16 + lane] : 0.0f;
    }
    float acc[4] = {0.f,0.f,0.f,0.f};
    {
      const int ownBase = isRow ? 0 : 64;     // own part of W row
      for (int kb = 0; kb < 64; kb += 4) {
        float4 w4 = *(const float4*)(Wrow + ownBase + kb);
        GATE_BATCH8(xcO, w4, kb);
      }
    }

    // ---- SYNC-IN (hidden under own GEMM): wait <=2 cross producer groups ----
    if (t > 0) {
      if (tid == 0) {
        int a = isRow ? ((c0 - t) & 31) : ((c0 + t) & 31);   // first cross chain
        unsigned* f1 = flg(p.ws, b, 1 - side, a >> 2);
        unsigned* f2 = flg(p.ws, b, 1 - side, ((a + 3) & 31) >> 2);
        const unsigned need = (unsigned)t;
        int guard = 0;
        while ((flag_load(f1) < need || flag_load(f2) < need) && ++guard < 4000000)
          __builtin_amdgcn_s_sleep(1);
      }
      __syncthreads();
    }

    // ---- phase A2: ISSUE cross loads, cover RTT with x GEMM, then cross GEMM ----
#pragma unroll
    for (int i = 0; i < 4; ++i) {
      int r = r8[i], cc = cc8[i];
      xcC[i] = isRow ? coh_load(&hcolR[(((cc << 5) | b) << 6) + lane])
                     : coh_load(&hrowR[(((r << 5) | b) << 6) + lane]);
    }
#pragma unroll
    for (int kb = 128; kb < 144; kb += 4) {    // x GEMM: covers cross-load RTT
      float4 w4 = *(const float4*)(Wrow + kb);
      GATE_BATCH8(xc2, w4, kb - 128);
    }
    {
      const int crossBase = isRow ? 64 : 0;    // cross part of W row
      for (int kb = 0; kb < 64; kb += 4) {
        float4 w4 = *(const float4*)(Wrow + crossBase + kb);
        GATE_BATCH8(xcC, w4, kb);
      }
    }
    if (tid < 224) {
      const bool isT = (tid >= 128 && tid < 192);
#pragma unroll
      for (int i = 0; i < 4; ++i) {
        float bm = (t < SNN && r8[i] <= t) ? 1.0f : 0.0f;
        float v = fmaf(bm, bias, acc[i]);
        gl[i][tid] = isT ? tanh_fast(v) : sigm_fast(v);
      }
    }
    __syncthreads();

    // ---- phase B: register-state update + cvec ----
#pragma unroll
    for (int i = 0; i < 4; ++i) {
      int cc = cc8[i];
      int tcd = t - cc;
      int ctI = (tcd >= 0 && tcd < OSLN) ? ((cc << 5) + tcd) : 0;
      const float* cp = p.ws + WS_COS + (ctI << 5) + f0;
      const float* sp = p.ws + WS_SIN + (ctI << 5) + f0;
      float csv[8], snv[8];
      *(float4*)(csv)     = *(const float4*)(cp);
      *(float4*)(csv + 4) = *(const float4*)(cp + 4);
      *(float4*)(snv)     = *(const float4*)(sp);
      *(float4*)(snv + 4) = *(const float4*)(sp + 4);
      float ug = gl[i][hh];
      float og = gl[i][64 + hh];
      float ig = gl[i][128 + hh];
      float amp = og * ig;
      float fr[8];
      *(float4*)(fr)     = *(const float4*)(&gl[i][192 + f0]);
      *(float4*)(fr + 4) = *(const float4*)(&gl[i][192 + f0 + 4]);
      float sq = 0.0f;
#pragma unroll
      for (int fi = 0; fi < 8; ++fi) {
        float ft = ug * fr[fi];
        rr[i][fi] = fmaf(ft, rr[i][fi], amp * csv[fi]);
        ri[i][fi] = fmaf(ft, ri[i][fi], amp * snv[fi]);
        sq = fmaf(fmaf(ri[i][fi], ri[i][fi], rr[i][fi] * rr[i][fi]), wfv[fi], sq);
      }
      sq += __shfl_xor(sq, 1);
      sq += __shfl_xor(sq, 2);
      if ((tid & 3) == 0) cvec[i][hh] = tanh_fast(sq + cbv);
    }
    __syncthreads();

    // ---- phase C: output matmul + h update + stores (slot = mg) ----
    float u0 = 0.0f;
    for (int k = 0; k < 64; k += 4) {
      float4 w4 = *(const float4*)(OW + k);
      u0 = fmaf(w4.x, cvec[mg][k],     u0);
      u0 = fmaf(w4.y, cvec[mg][k + 1], u0);
      u0 = fmaf(w4.z, cvec[mg][k + 2], u0);
      u0 = fmaf(w4.w, cvec[mg][k + 3], u0);
    }
    {
      const int i = mg;
      float ug = gl[i][hp];
      float ig = gl[i][128 + hp];
      float hOld = hown[i][hp];          // own previous h (one-to-one read/write)
      float cval = cvec[i][hp];
      float pre = (1.0f - ug) * hOld + ug * ig + u0 + ob;
      float hn = sigm_fast(pre) * cval;
      hown[i][hp] = hn;                  // persist own h locally for step t+1
      int r = r8[i], cc = cc8[i];
      int n = (r << 5) | b;
      if (isRow) {
        coh_store(&hrowW[(n << 6) + hp], hn);                 // for col-side readers
        p.out[(((size_t)n * LTN) + t) * 128 + hp] = hn;
        if (t >= 31 && r == t - 31)
          p.out[OUT_HR + (((b << 5) | r) << 6) + hp] = hn;
      } else {
        coh_store(&hcolW[(((cc << 5) | b) << 6) + hp], hn);   // for row-side readers
        p.out[(((size_t)n * LTN) + t) * 128 + 64 + hp] = hn;
        if (t >= 31 && r == 31)
          p.out[OUT_HC + (((b << 5) | (t - 31)) << 6) + hp] = hn;
      }
    }

    // ---- SYNC-OUT: drain stores (syncthreads emits vmcnt(0)), publish flag ----
    if (t < LTN - 1) {
      __syncthreads();
      if (tid == 0) flag_store(fOwn, (unsigned)(t + 1));
    }
  }
}

extern "C" void kernel_launch(void* const* d_in, const int* in_sizes, int n_in,
                              void* d_out, int out_size, void* d_ws, size_t ws_size,
                              hipStream_t stream) {
  KParams p;
  p.x    = (const float*)d_in[0];
  p.Wf   = (const float*)d_in[1];
  p.Wq   = (const float*)d_in[2];
  p.Bg   = (const float*)d_in[3];
  p.Bq   = (const float*)d_in[4];
  p.rcw  = (const float*)d_in[5];
  p.rcb  = (const float*)d_in[6];
  p.ccw  = (const float*)d_in[7];
  p.ccb  = (const float*)d_in[8];
  p.r_ow = (const float*)d_in[9];
  p.r_ob = (const float*)d_in[10];
  p.c_ow = (const float*)d_in[11];
  p.c_ob = (const float*)d_in[12];
  p.ws   = (float*)d_ws;
  p.out  = (float*)d_out;

  hipLaunchKernelGGL(init_kernel, dim3(256), dim3(256), 0, stream, p.ws);
  hipLaunchKernelGGL(fused_kernel, dim3(512), dim3(256), 0, stream, p);
}